// Round 2
// baseline (792.786 us; speedup 1.0000x reference)
//
#include <hip/hip_runtime.h>

// SeqFCEncoder: out = relu(drop(x) @ W1 + b1) @ W2 + b2
// B=262144 rows, L=50 (K-padded to 64), H=1024 (16 chunks of 64), E=256.
// bf16 MFMA 16x16x32 fused pipeline; weights pre-packed into fragment order in ws.
// Dropout: JAX threefry2x32, jax_threefry_partitionable=True semantics:
//   per flat element j: counter words (hi=0, lo=j), key (0,42), bits = out0 ^ out1.
//
// v2 structure (LDS-minimal) — resubmission: previous round died on a container
// infra error ("MI355X container failed twice") with no kernel-level signal.
//  - x held in registers as GEMM1 B-frags (one row per lane); dropout + first-neg in-register.
//  - GEMM1 computed SWAPPED: mfma(W1^T-as-A, x-as-B) -> h emerges with lane&15 = batch row,
//    i.e. already in GEMM2 A-frag lane order -> h transpose costs 4 ds_write_b64/wave/chunk.
//  - lds_h double-buffered (2 x 16KB) -> ONE barrier per chunk.
//  - W2 B-frags streamed directly from global (packed, L1/L2-hot) -> no lds_w2, no commit.

typedef __attribute__((ext_vector_type(8))) short short8;   // 8 bf16 = one MFMA operand frag
typedef __attribute__((ext_vector_type(4))) float f32x4;    // MFMA accumulator frag

__device__ __forceinline__ unsigned short f2bf(float f) {
  unsigned u = __float_as_uint(f);
  u += 0x7fffu + ((u >> 16) & 1u);           // round-to-nearest-even
  return (unsigned short)(u >> 16);
}

__device__ __forceinline__ unsigned rotl_(unsigned x, int d) {
  return (x << d) | (x >> (32 - d));
}

// Partitionable threefry2x32: key=(0,42), counter=(0, j); 20 rounds; bits=v0^v1.
// uniform: bitcast((bits>>9)|0x3f800000) - 1.0f;  drop iff u < 0.2f
__device__ __forceinline__ bool drop_rand(unsigned j) {
  const unsigned k0 = 0u, k1 = 42u, k2 = 0x1BD11BDAu ^ 42u;
  unsigned v0 = 0u + k0;          // counter hi word = 0
  unsigned v1 = j + k1;           // counter lo word = flat index
#define MIX(rot) { v0 += v1; v1 = rotl_(v1, rot); v1 ^= v0; }
  MIX(13) MIX(15) MIX(26) MIX(6)   v0 += k1; v1 += k2 + 1u;
  MIX(17) MIX(29) MIX(16) MIX(24)  v0 += k2; v1 += k0 + 2u;
  MIX(13) MIX(15) MIX(26) MIX(6)   v0 += k0; v1 += k1 + 3u;
  MIX(17) MIX(29) MIX(16) MIX(24)  v0 += k1; v1 += k2 + 4u;
  MIX(13) MIX(15) MIX(26) MIX(6)   v0 += k2; v1 += k0 + 5u;
#undef MIX
  unsigned bits = v0 ^ v1;
  float u = __uint_as_float((bits >> 9) | 0x3f800000u) - 1.0f;
  return u < 0.2f;
}

// ---------------------------------------------------------------------------
// Prep: pack W1 (50x1024, K-padded to 64) and W2 (1024x256) as bf16 in MFMA
// fragment order. Fragment (lane, j) holds W[kblk*32 + (lane>>4)*8 + j][nt*16 + (lane&15)].
//   pW1 @ ws[0]:      [nblk 0..63][kb 0..1][lane][j]          = 65536 elems (128 KB)
//   pW2 @ ws[65536]:  [c 0..15][kb 0..1][nt 0..15][lane][j]   = 262144 elems (512 KB)
// NOTE: this layout serves as BOTH the A-operand (swapped GEMM1) and B-operand
// (GEMM2) fragment, since A-frag and B-frag lane layouts are identical.
// ---------------------------------------------------------------------------
__global__ void pack_weights(const float* __restrict__ W1, const float* __restrict__ W2,
                             unsigned short* __restrict__ ws) {
  int t = blockIdx.x * 256 + threadIdx.x;   // 0..40959
  if (t < 8192) {
    int nblk = t >> 7, kb = (t >> 6) & 1, lane = t & 63;
    int kbase = kb * 32 + ((lane >> 4) * 8);
    int col = nblk * 16 + (lane & 15);
    short8 vv;
#pragma unroll
    for (int j = 0; j < 8; ++j) {
      int k = kbase + j;
      vv[j] = (short)((k < 50) ? f2bf(W1[k * 1024 + col]) : (unsigned short)0);
    }
    *(short8*)&ws[t * 8] = vv;
  } else {
    int t2 = t - 8192;                       // 0..32767
    int c = t2 >> 11, kb = (t2 >> 10) & 1, nt = (t2 >> 6) & 15, lane = t2 & 63;
    int kbase = c * 64 + kb * 32 + ((lane >> 4) * 8);
    int e = nt * 16 + (lane & 15);
    short8 vv;
#pragma unroll
    for (int j = 0; j < 8; ++j) vv[j] = (short)f2bf(W2[(size_t)(kbase + j) * 256 + e]);
    *(short8*)&ws[65536 + t2 * 8] = vv;
  }
}

// ---------------------------------------------------------------------------
// Fused MLP. 512 threads (8 waves), 128 rows/block, grid 2048.
// Wave roles:
//   GEMM1: wave = row-group rg (16 rows), computes h for its rows x 64 H-cols (swapped).
//   GEMM2: wave = (rg2 = wave>>1: 32 rows) x (cg = wave&1: 128 E-cols), acc[2][8].
// LDS: lds_h[2][16KB] double-buffered h A-frags only. 1 barrier per chunk.
// ---------------------------------------------------------------------------
__global__ __launch_bounds__(512, 4) void mlp_fused(
    const float* __restrict__ seq, const float* __restrict__ b1,
    const float* __restrict__ b2, const unsigned short* __restrict__ ws,
    float* __restrict__ out) {
  __shared__ __align__(16) unsigned short lds_h[2][8192];   // 2 x 16 KB

  const int tid  = threadIdx.x;
  const int lane = tid & 63;
  const int wave = tid >> 6;          // 0..7
  const int q    = lane >> 4;         // quad 0..3
  const int l15  = lane & 15;
  const int m0   = blockIdx.x * 128;
  const unsigned short* pW1 = ws;
  const unsigned short* pW2 = ws + 65536;

  // ---- phase 0: x row-fragments into registers; first-neg scan; threefry dropout
  // Lane (l15, q) owns row (m0 + wave*16 + l15), k-octets [8q..8q+7] and [32+8q..39+8q].
  short8 xb[2];                        // GEMM1 B-frags: x[row][kb*32 + 8q + j]
  {
    const int row = m0 + wave * 16 + l15;
    const float* xrow = seq + (size_t)row * 50;
    float xv[2][8];
    unsigned long long nm = 0ull;
#pragma unroll
    for (int kb = 0; kb < 2; ++kb) {
#pragma unroll
      for (int jp = 0; jp < 4; ++jp) {
        const int k = kb * 32 + q * 8 + jp * 2;   // even, 8B-aligned
        float2 v;
        if (k < 50) v = *(const float2*)&xrow[k];
        else        v = make_float2(0.f, 0.f);    // K-pad with 0
        xv[kb][jp * 2]     = v.x;
        xv[kb][jp * 2 + 1] = v.y;
        if (v.x == -1.0f) nm |= 1ull << k;
        if (v.y == -1.0f) nm |= 1ull << (k + 1);
      }
    }
    // row's 4 owner lanes are {l15, l15+16, l15+32, l15+48}
    nm |= __shfl_xor(nm, 16);
    nm |= __shfl_xor(nm, 32);
    const int fn   = nm ? __builtin_ctzll(nm) : 64;   // first_neg (>=50 => all valid)
    const int kmax = fn < 50 ? fn : 50;
    const unsigned jbase = (unsigned)row * 50u;
#pragma unroll
    for (int kb = 0; kb < 2; ++kb) {
      short8 vv;
#pragma unroll
      for (int j = 0; j < 8; ++j) {
        const int k = kb * 32 + q * 8 + j;
        float v = xv[kb][j];
        if (k < kmax && drop_rand(jbase + (unsigned)k)) v = 0.0f;
        vv[j] = (short)f2bf(v);
      }
      xb[kb] = vv;
    }
  }

  f32x4 acc[2][8];
#pragma unroll
  for (int mt = 0; mt < 2; ++mt)
#pragma unroll
    for (int ni = 0; ni < 8; ++ni) acc[mt][ni] = f32x4{0.f, 0.f, 0.f, 0.f};

  const int rg2 = wave >> 1;     // GEMM2 rows: rg2*32 .. rg2*32+31
  const int cg  = wave & 1;      // GEMM2 cols: cg*128 .. cg*128+127

  for (int c = 0; c < 16; ++c) {
    // ---- GEMM1 (swapped): hacc[hi] holds h[row = tile*16+l15][hcol = hi*16 + 4q + r]
    f32x4 hacc[4];
#pragma unroll
    for (int hi = 0; hi < 4; ++hi) hacc[hi] = f32x4{0.f, 0.f, 0.f, 0.f};
#pragma unroll
    for (int kb = 0; kb < 2; ++kb) {
      short8 wa[4];
#pragma unroll
      for (int hi = 0; hi < 4; ++hi)
        wa[hi] = *(const short8*)&pW1[(size_t)(((c * 4 + hi) * 2 + kb) * 64 + lane) * 8];
#pragma unroll
      for (int hi = 0; hi < 4; ++hi)
        hacc[hi] = __builtin_amdgcn_mfma_f32_16x16x32_bf16(wa[hi], xb[kb], hacc[hi], 0, 0, 0);
    }

    // ---- bias + relu + bf16-pack; vector ds_write_b64 straight into A-frag layout
    // hcol64 = hi*16 + 4q + r  ->  kb = hi>>1, q' = ((hi&1)<<1)|(q>>1), j0 = 4*(q&1)
    unsigned short* hb = &lds_h[c & 1][0];
#pragma unroll
    for (int hi = 0; hi < 4; ++hi) {
      const f32x4 bv = *(const f32x4*)&b1[c * 64 + hi * 16 + q * 4];
      const float v0 = fmaxf(hacc[hi][0] + bv[0], 0.f);
      const float v1 = fmaxf(hacc[hi][1] + bv[1], 0.f);
      const float v2 = fmaxf(hacc[hi][2] + bv[2], 0.f);
      const float v3 = fmaxf(hacc[hi][3] + bv[3], 0.f);
      const unsigned w0 = (unsigned)f2bf(v0) | ((unsigned)f2bf(v1) << 16);
      const unsigned w1 = (unsigned)f2bf(v2) | ((unsigned)f2bf(v3) << 16);
      const int kb   = hi >> 1;
      const int qp   = ((hi & 1) << 1) | (q >> 1);
      const int elem = (wave * 2 + kb) * 64 + qp * 16 + l15;
      uint2 val; val.x = w0; val.y = w1;
      *(uint2*)&hb[elem * 8 + (q & 1) * 4] = val;   // 8B-aligned ds_write_b64
    }

    __syncthreads();   // the ONLY barrier per chunk (h double-buffered)

    // ---- GEMM2: acc += h_chunk @ W2[64c..64c+64, :); A from LDS, B from global (hot)
#pragma unroll
    for (int kb = 0; kb < 2; ++kb) {
      short8 ha[2];
#pragma unroll
      for (int mt = 0; mt < 2; ++mt)
        ha[mt] = *(const short8*)&lds_h[c & 1][(size_t)(((rg2 * 2 + mt) * 2 + kb) * 64 + lane) * 8];
#pragma unroll
      for (int ng = 0; ng < 2; ++ng) {
        short8 wb[4];
#pragma unroll
        for (int ni = 0; ni < 4; ++ni) {
          const int nt = cg * 8 + ng * 4 + ni;
          wb[ni] = *(const short8*)&pW2[(size_t)(((c * 2 + kb) * 16 + nt) * 64 + lane) * 8];
        }
#pragma unroll
        for (int mt = 0; mt < 2; ++mt)
#pragma unroll
          for (int ni = 0; ni < 4; ++ni)
            acc[mt][ng * 4 + ni] =
                __builtin_amdgcn_mfma_f32_16x16x32_bf16(ha[mt], wb[ni], acc[mt][ng * 4 + ni], 0, 0, 0);
      }
    }
  }

  // ---- epilogue: + b2, fp32 store (C-layout: 4-row x 16-col segments)
#pragma unroll
  for (int ng = 0; ng < 8; ++ng) {
    const int e = cg * 128 + ng * 16 + l15;
    const float b2v = b2[e];
#pragma unroll
    for (int mt = 0; mt < 2; ++mt) {
      const int rbase = m0 + rg2 * 32 + mt * 16 + q * 4;
#pragma unroll
      for (int r = 0; r < 4; ++r)
        out[(size_t)(rbase + r) * 256 + e] = acc[mt][ng][r] + b2v;
    }
  }
}

extern "C" void kernel_launch(void* const* d_in, const int* in_sizes, int n_in,
                              void* d_out, int out_size, void* d_ws, size_t ws_size,
                              hipStream_t stream) {
  const float* seq = (const float*)d_in[0];
  const float* W1  = (const float*)d_in[1];
  const float* b1  = (const float*)d_in[2];
  const float* W2  = (const float*)d_in[3];
  const float* b2  = (const float*)d_in[4];
  unsigned short* ws = (unsigned short*)d_ws;   // 655360 bytes used
  float* out = (float*)d_out;

  hipLaunchKernelGGL(pack_weights, dim3(160), dim3(256), 0, stream, W1, W2, ws);
  hipLaunchKernelGGL(mlp_fused, dim3(2048), dim3(512), 0, stream, seq, b1, b2, ws, out);
}

// Round 3
// 598.346 us; speedup vs baseline: 1.3250x; 1.3250x over previous
//
#include <hip/hip_runtime.h>

// SeqFCEncoder: out = relu(drop(x) @ W1 + b1) @ W2 + b2
// B=262144 rows, L=50 (K-padded to 64), H=1024 (16 chunks of 64), E=256.
// bf16 MFMA 16x16x32 fused pipeline; weights pre-packed into fragment order in ws.
//
// v3 = v1's W2 latency-hiding pipeline (global->regs early, commit->LDS late,
//      consume from LDS) + v2's register-x / swapped-GEMM1 / vector-h-write.
//  - x in registers as GEMM1 B-frags; dropout + first-neg in-register.
//  - GEMM1 swapped: mfma(W1-as-A, x-as-B) -> h lands in GEMM2 A-frag lane order;
//    h transpose = 4 ds_write_b64 per wave per chunk.
//  - W2 chunk: stgA/stgB register double-buffer; issue W2(c+1) at TOP of chunk c
//    (~400cy before the barrier drain), commit W2(c) to LDS after GEMM1.
//  - lds_h and lds_w2 both double-buffered -> ONE __syncthreads per chunk.
//  - GEMM2 wave tile 64 rows x 64 cols (8 waves = 128x256 block tile).

typedef __attribute__((ext_vector_type(8))) short short8;   // 8 bf16 = one MFMA operand frag
typedef __attribute__((ext_vector_type(4))) float f32x4;    // MFMA accumulator frag

__device__ __forceinline__ unsigned short f2bf(float f) {
  unsigned u = __float_as_uint(f);
  u += 0x7fffu + ((u >> 16) & 1u);           // round-to-nearest-even
  return (unsigned short)(u >> 16);
}

__device__ __forceinline__ unsigned rotl_(unsigned x, int d) {
  return (x << d) | (x >> (32 - d));
}

// Partitionable threefry2x32: key=(0,42), counter=(0, j); 20 rounds; bits=v0^v1.
// uniform: bitcast((bits>>9)|0x3f800000) - 1.0f;  drop iff u < 0.2f
__device__ __forceinline__ bool drop_rand(unsigned j) {
  const unsigned k0 = 0u, k1 = 42u, k2 = 0x1BD11BDAu ^ 42u;
  unsigned v0 = 0u + k0;          // counter hi word = 0
  unsigned v1 = j + k1;           // counter lo word = flat index
#define MIX(rot) { v0 += v1; v1 = rotl_(v1, rot); v1 ^= v0; }
  MIX(13) MIX(15) MIX(26) MIX(6)   v0 += k1; v1 += k2 + 1u;
  MIX(17) MIX(29) MIX(16) MIX(24)  v0 += k2; v1 += k0 + 2u;
  MIX(13) MIX(15) MIX(26) MIX(6)   v0 += k0; v1 += k1 + 3u;
  MIX(17) MIX(29) MIX(16) MIX(24)  v0 += k1; v1 += k2 + 4u;
  MIX(13) MIX(15) MIX(26) MIX(6)   v0 += k2; v1 += k0 + 5u;
#undef MIX
  unsigned bits = v0 ^ v1;
  float u = __uint_as_float((bits >> 9) | 0x3f800000u) - 1.0f;
  return u < 0.2f;
}

// ---------------------------------------------------------------------------
// Prep: pack W1 (50x1024, K-padded to 64) and W2 (1024x256) as bf16 in MFMA
// fragment order. Fragment (lane, j) holds W[kblk*32 + (lane>>4)*8 + j][nt*16 + (lane&15)].
//   pW1 @ ws[0]:      [nblk 0..63][kb 0..1][lane][j]          = 65536 elems (128 KB)
//   pW2 @ ws[65536]:  [c 0..15][kb 0..1][nt 0..15][lane][j]   = 262144 elems (512 KB)
// A-frag and B-frag lane layouts are identical, so pW1 serves as the A operand
// of the swapped GEMM1 and pW2 as the B operand of GEMM2.
// ---------------------------------------------------------------------------
__global__ void pack_weights(const float* __restrict__ W1, const float* __restrict__ W2,
                             unsigned short* __restrict__ ws) {
  int t = blockIdx.x * 256 + threadIdx.x;   // 0..40959
  if (t < 8192) {
    int nblk = t >> 7, kb = (t >> 6) & 1, lane = t & 63;
    int kbase = kb * 32 + ((lane >> 4) * 8);
    int col = nblk * 16 + (lane & 15);
    short8 vv;
#pragma unroll
    for (int j = 0; j < 8; ++j) {
      int k = kbase + j;
      vv[j] = (short)((k < 50) ? f2bf(W1[k * 1024 + col]) : (unsigned short)0);
    }
    *(short8*)&ws[t * 8] = vv;
  } else {
    int t2 = t - 8192;                       // 0..32767
    int c = t2 >> 11, kb = (t2 >> 10) & 1, nt = (t2 >> 6) & 15, lane = t2 & 63;
    int kbase = c * 64 + kb * 32 + ((lane >> 4) * 8);
    int e = nt * 16 + (lane & 15);
    short8 vv;
#pragma unroll
    for (int j = 0; j < 8; ++j) vv[j] = (short)f2bf(W2[(size_t)(kbase + j) * 256 + e]);
    *(short8*)&ws[65536 + t2 * 8] = vv;
  }
}

// ---------------------------------------------------------------------------
// Fused MLP. 512 threads (8 waves), 128 rows/block, grid 2048.
//   GEMM1: wave w owns rows w*16..w*16+15 (swapped MFMA, 8 MFMA/chunk).
//   GEMM2: wave = (rg = wave>>2: 64 rows) x (cgr = wave&3: 64 E-cols), acc[4][4].
// LDS: lds_h[2][16KB] + lds_w2[2][32KB] = 96 KB; ONE barrier per chunk.
// ---------------------------------------------------------------------------
__global__ __launch_bounds__(512, 2) void mlp_fused(
    const float* __restrict__ seq, const float* __restrict__ b1,
    const float* __restrict__ b2, const unsigned short* __restrict__ ws,
    float* __restrict__ out) {
  __shared__ __align__(16) unsigned short lds_h[2][8192];     // 2 x 16 KB
  __shared__ __align__(16) unsigned short lds_w2[2][16384];   // 2 x 32 KB

  const int tid  = threadIdx.x;
  const int lane = tid & 63;
  const int wave = tid >> 6;          // 0..7
  const int q    = lane >> 4;         // quad 0..3
  const int l15  = lane & 15;
  const int m0   = blockIdx.x * 128;
  const unsigned short* pW1 = ws;
  const unsigned short* pW2 = ws + 65536;

  // ---- prologue: issue W2 chunk 0 loads; they complete during the x phase.
  short8 stgA[4], stgB[4];
#pragma unroll
  for (int it = 0; it < 4; ++it)
    stgA[it] = *(const short8*)&pW2[(size_t)(it * 512 + tid) * 8];

  // ---- phase 0: x row-fragments into registers; first-neg scan; threefry dropout
  // Lane (l15, q) owns row (m0 + wave*16 + l15), k-octets [8q..8q+7] and [32+8q..39+8q].
  short8 xb[2];                        // GEMM1 B-frags: x[row][kb*32 + 8q + j]
  {
    const int row = m0 + wave * 16 + l15;
    const float* xrow = seq + (size_t)row * 50;
    float xv[2][8];
    unsigned long long nm = 0ull;
#pragma unroll
    for (int kb = 0; kb < 2; ++kb) {
#pragma unroll
      for (int jp = 0; jp < 4; ++jp) {
        const int k = kb * 32 + q * 8 + jp * 2;   // even, 8B-aligned
        float2 v;
        if (k < 50) v = *(const float2*)&xrow[k];
        else        v = make_float2(0.f, 0.f);    // K-pad with 0
        xv[kb][jp * 2]     = v.x;
        xv[kb][jp * 2 + 1] = v.y;
        if (v.x == -1.0f) nm |= 1ull << k;
        if (v.y == -1.0f) nm |= 1ull << (k + 1);
      }
    }
    // row's 4 owner lanes are {l15, l15+16, l15+32, l15+48}
    nm |= __shfl_xor(nm, 16);
    nm |= __shfl_xor(nm, 32);
    const int fn   = nm ? __builtin_ctzll(nm) : 64;   // first_neg (>=50 => all valid)
    const int kmax = fn < 50 ? fn : 50;
    const unsigned jbase = (unsigned)row * 50u;
#pragma unroll
    for (int kb = 0; kb < 2; ++kb) {
      short8 vv;
#pragma unroll
      for (int j = 0; j < 8; ++j) {
        const int k = kb * 32 + q * 8 + j;
        float v = xv[kb][j];
        if (k < kmax && drop_rand(jbase + (unsigned)k)) v = 0.0f;
        vv[j] = (short)f2bf(v);
      }
      xb[kb] = vv;
    }
  }

  f32x4 acc[4][4];
#pragma unroll
  for (int mt = 0; mt < 4; ++mt)
#pragma unroll
    for (int ni = 0; ni < 4; ++ni) acc[mt][ni] = f32x4{0.f, 0.f, 0.f, 0.f};

  const int rg  = wave >> 2;     // GEMM2 rows: rg*64 .. rg*64+63
  const int cgr = wave & 3;      // GEMM2 cols: cgr*64 .. cgr*64+63

  // One chunk step. SCUR holds W2(C) (loaded last step / prologue): commit it to
  // LDS after GEMM1. SNXT gets W2(C+1) issued at the top (hidden under GEMM1+pack).
  // PAR = C&1 selects the LDS double buffers (compile-time via 2x unroll).
#define CHUNK_STEP(C, SCUR, SNXT, PAR)                                               \
  {                                                                                  \
    const int c_ = (C);                                                              \
    /* GEMM1 A-frags (pW1, L1-hot) */                                                \
    short8 wa[2][4];                                                                 \
    _Pragma("unroll")                                                                \
    for (int kb = 0; kb < 2; ++kb)                                                   \
      _Pragma("unroll")                                                              \
      for (int hi = 0; hi < 4; ++hi)                                                 \
        wa[kb][hi] = *(const short8*)&pW1[(size_t)(((c_ * 4 + hi) * 2 + kb) * 64 + lane) * 8]; \
    /* issue next W2 chunk: in flight across GEMM1+pack, drained at the barrier */   \
    _Pragma("unroll")                                                                \
    for (int it = 0; it < 4; ++it)                                                   \
      SNXT[it] = *(const short8*)&pW2[(size_t)((c_ + 1) & 15) * 16384 +              \
                                      (size_t)(it * 512 + tid) * 8];                 \
    /* GEMM1 (swapped): hacc[hi] = h[row = wave*16+l15][hcol = hi*16 + 4q + r] */    \
    f32x4 hacc[4];                                                                   \
    _Pragma("unroll")                                                                \
    for (int hi = 0; hi < 4; ++hi) hacc[hi] = f32x4{0.f, 0.f, 0.f, 0.f};             \
    _Pragma("unroll")                                                                \
    for (int kb = 0; kb < 2; ++kb)                                                   \
      _Pragma("unroll")                                                              \
      for (int hi = 0; hi < 4; ++hi)                                                 \
        hacc[hi] = __builtin_amdgcn_mfma_f32_16x16x32_bf16(wa[kb][hi], xb[kb],       \
                                                           hacc[hi], 0, 0, 0);       \
    /* bias + relu + bf16 pack -> A-frag layout, 4 x ds_write_b64 */                 \
    {                                                                                \
      unsigned short* hb = &lds_h[PAR][0];                                           \
      _Pragma("unroll")                                                              \
      for (int hi = 0; hi < 4; ++hi) {                                               \
        const f32x4 bv = *(const f32x4*)&b1[c_ * 64 + hi * 16 + q * 4];              \
        const float v0 = fmaxf(hacc[hi][0] + bv[0], 0.f);                            \
        const float v1 = fmaxf(hacc[hi][1] + bv[1], 0.f);                            \
        const float v2 = fmaxf(hacc[hi][2] + bv[2], 0.f);                            \
        const float v3 = fmaxf(hacc[hi][3] + bv[3], 0.f);                            \
        const unsigned w0 = (unsigned)f2bf(v0) | ((unsigned)f2bf(v1) << 16);         \
        const unsigned w1 = (unsigned)f2bf(v2) | ((unsigned)f2bf(v3) << 16);         \
        const int kbx  = hi >> 1;                                                    \
        const int qp   = ((hi & 1) << 1) | (q >> 1);                                 \
        const int elem = (wave * 2 + kbx) * 64 + qp * 16 + l15;                      \
        uint2 val; val.x = w0; val.y = w1;                                           \
        *(uint2*)&hb[elem * 8 + (q & 1) * 4] = val;                                  \
      }                                                                              \
    }                                                                                \
    /* commit W2(C) regs -> LDS (layout == pW2 chunk layout) */                      \
    _Pragma("unroll")                                                                \
    for (int it = 0; it < 4; ++it)                                                   \
      *(short8*)&lds_w2[PAR][(size_t)(it * 512 + tid) * 8] = SCUR[it];               \
    __syncthreads();   /* h + w2 visible; WAR vs chunk C-2 handled by barrier C-1 */ \
    /* GEMM2: acc += h_chunk @ W2[64c..64c+64, :) entirely from LDS */               \
    _Pragma("unroll")                                                                \
    for (int kb = 0; kb < 2; ++kb) {                                                 \
      short8 ha[4], wb[4];                                                           \
      _Pragma("unroll")                                                              \
      for (int mt = 0; mt < 4; ++mt)                                                 \
        ha[mt] = *(const short8*)&lds_h[PAR][(size_t)(((rg * 4 + mt) * 2 + kb) * 64 + lane) * 8]; \
      _Pragma("unroll")                                                              \
      for (int ni = 0; ni < 4; ++ni)                                                 \
        wb[ni] = *(const short8*)&lds_w2[PAR][(size_t)((kb * 16 + cgr * 4 + ni) * 64 + lane) * 8]; \
      _Pragma("unroll")                                                              \
      for (int mt = 0; mt < 4; ++mt)                                                 \
        _Pragma("unroll")                                                            \
        for (int ni = 0; ni < 4; ++ni)                                               \
          acc[mt][ni] = __builtin_amdgcn_mfma_f32_16x16x32_bf16(ha[mt], wb[ni],      \
                                                                acc[mt][ni], 0, 0, 0); \
    }                                                                                \
  }

  for (int ch = 0; ch < 8; ++ch) {
    CHUNK_STEP(2 * ch,     stgA, stgB, 0)
    CHUNK_STEP(2 * ch + 1, stgB, stgA, 1)
  }
#undef CHUNK_STEP

  // ---- epilogue: + b2, fp32 store (C-layout: 4-row x 16-col segments)
#pragma unroll
  for (int ni = 0; ni < 4; ++ni) {
    const int e = cgr * 64 + ni * 16 + l15;
    const float b2v = b2[e];
#pragma unroll
    for (int mt = 0; mt < 4; ++mt) {
      const int rbase = m0 + rg * 64 + mt * 16 + q * 4;
#pragma unroll
      for (int r = 0; r < 4; ++r)
        out[(size_t)(rbase + r) * 256 + e] = acc[mt][ni][r] + b2v;
    }
  }
}

extern "C" void kernel_launch(void* const* d_in, const int* in_sizes, int n_in,
                              void* d_out, int out_size, void* d_ws, size_t ws_size,
                              hipStream_t stream) {
  const float* seq = (const float*)d_in[0];
  const float* W1  = (const float*)d_in[1];
  const float* b1  = (const float*)d_in[2];
  const float* W2  = (const float*)d_in[3];
  const float* b2  = (const float*)d_in[4];
  unsigned short* ws = (unsigned short*)d_ws;   // 655360 bytes used
  float* out = (float*)d_out;

  hipLaunchKernelGGL(pack_weights, dim3(160), dim3(256), 0, stream, W1, W2, ws);
  hipLaunchKernelGGL(mlp_fused, dim3(2048), dim3(512), 0, stream, seq, b1, b2, ws, out);
}

// Round 4
// 526.117 us; speedup vs baseline: 1.5069x; 1.1373x over previous
//
#include <hip/hip_runtime.h>

// SeqFCEncoder: out = relu(drop(x) @ W1 + b1) @ W2 + b2
// B=262144 rows, L=50 (K-padded to 64), H=1024 (16 chunks of 64), E=256.
// bf16 MFMA 16x16x32 fused pipeline; weights pre-packed into fragment order in ws.
//
// v4: restore 2 blocks/CU (the lever v1 had and v2/v3 lost):
//  - LDS exactly 80 KB: single lds_h (16KB) + double-buffered lds_w2 (2x32KB).
//  - W2 staged via __builtin_amdgcn_global_load_lds width=16 (no stg VGPRs, no
//    ds_write commit, async until the consuming barrier's vmcnt drain).
//  - Regs <= 128/wave (__launch_bounds__(512,4)) -> 16 waves/CU.
//  - x in registers as GEMM1 B-frags; swapped GEMM1; 4x ds_write_b64 h-transpose.
//  - 2 barriers/chunk: A (h + W2(c) ready) and B (WAR on lds_h / lds_w2[par]).
//    DMA W2(c+1) issued right after A -> a full GEMM2+GEMM1+pack before its
//    consuming drain at A(c+1).

typedef __attribute__((ext_vector_type(8))) short short8;   // 8 bf16 = one MFMA operand frag
typedef __attribute__((ext_vector_type(4))) float f32x4;    // MFMA accumulator frag

__device__ __forceinline__ unsigned short f2bf(float f) {
  unsigned u = __float_as_uint(f);
  u += 0x7fffu + ((u >> 16) & 1u);           // round-to-nearest-even
  return (unsigned short)(u >> 16);
}

__device__ __forceinline__ unsigned rotl_(unsigned x, int d) {
  return (x << d) | (x >> (32 - d));
}

// Partitionable threefry2x32: key=(0,42), counter=(0, j); 20 rounds; bits=v0^v1.
// uniform: bitcast((bits>>9)|0x3f800000) - 1.0f;  drop iff u < 0.2f
__device__ __forceinline__ bool drop_rand(unsigned j) {
  const unsigned k0 = 0u, k1 = 42u, k2 = 0x1BD11BDAu ^ 42u;
  unsigned v0 = 0u + k0;          // counter hi word = 0
  unsigned v1 = j + k1;           // counter lo word = flat index
#define MIX(rot) { v0 += v1; v1 = rotl_(v1, rot); v1 ^= v0; }
  MIX(13) MIX(15) MIX(26) MIX(6)   v0 += k1; v1 += k2 + 1u;
  MIX(17) MIX(29) MIX(16) MIX(24)  v0 += k2; v1 += k0 + 2u;
  MIX(13) MIX(15) MIX(26) MIX(6)   v0 += k0; v1 += k1 + 3u;
  MIX(17) MIX(29) MIX(16) MIX(24)  v0 += k1; v1 += k2 + 4u;
  MIX(13) MIX(15) MIX(26) MIX(6)   v0 += k2; v1 += k0 + 5u;
#undef MIX
  unsigned bits = v0 ^ v1;
  float u = __uint_as_float((bits >> 9) | 0x3f800000u) - 1.0f;
  return u < 0.2f;
}

// Async 16B global -> LDS (DMA): per-lane global src, wave-uniform LDS base;
// HW writes lds_base + lane*16. Counts toward vmcnt.
__device__ __forceinline__ void gload_lds16(const unsigned short* g, unsigned short* l) {
  __builtin_amdgcn_global_load_lds(
      (const __attribute__((address_space(1))) unsigned int*)g,
      (__attribute__((address_space(3))) unsigned int*)l, 16, 0, 0);
}

// ---------------------------------------------------------------------------
// Prep: pack W1 (50x1024, K-padded to 64) and W2 (1024x256) as bf16 in MFMA
// fragment order. Fragment (lane, j) holds W[kblk*32 + (lane>>4)*8 + j][nt*16 + (lane&15)].
//   pW1 @ ws[0]:      [nblk 0..63][kb 0..1][lane][j]          = 65536 elems (128 KB)
//   pW2 @ ws[65536]:  [c 0..15][kb 0..1][nt 0..15][lane][j]   = 262144 elems (512 KB)
// A-frag and B-frag lane layouts are identical, so pW1 serves as the A operand
// of the swapped GEMM1 and pW2 as the B operand of GEMM2.
// ---------------------------------------------------------------------------
__global__ void pack_weights(const float* __restrict__ W1, const float* __restrict__ W2,
                             unsigned short* __restrict__ ws) {
  int t = blockIdx.x * 256 + threadIdx.x;   // 0..40959
  if (t < 8192) {
    int nblk = t >> 7, kb = (t >> 6) & 1, lane = t & 63;
    int kbase = kb * 32 + ((lane >> 4) * 8);
    int col = nblk * 16 + (lane & 15);
    short8 vv;
#pragma unroll
    for (int j = 0; j < 8; ++j) {
      int k = kbase + j;
      vv[j] = (short)((k < 50) ? f2bf(W1[k * 1024 + col]) : (unsigned short)0);
    }
    *(short8*)&ws[t * 8] = vv;
  } else {
    int t2 = t - 8192;                       // 0..32767
    int c = t2 >> 11, kb = (t2 >> 10) & 1, nt = (t2 >> 6) & 15, lane = t2 & 63;
    int kbase = c * 64 + kb * 32 + ((lane >> 4) * 8);
    int e = nt * 16 + (lane & 15);
    short8 vv;
#pragma unroll
    for (int j = 0; j < 8; ++j) vv[j] = (short)f2bf(W2[(size_t)(kbase + j) * 256 + e]);
    *(short8*)&ws[65536 + t2 * 8] = vv;
  }
}

// ---------------------------------------------------------------------------
// Fused MLP. 512 threads (8 waves), 128 rows/block, grid 2048, 2 blocks/CU.
//   GEMM1: wave w owns rows w*16..w*16+15 (swapped MFMA, 8 MFMA/chunk).
//   GEMM2: wave = (rg = wave>>2: 64 rows) x (cgr = wave&3: 64 E-cols), acc[4][4].
// LDS: lds_h[16KB] + lds_w2[2][32KB] = 80 KB exactly.
// ---------------------------------------------------------------------------
__global__ __launch_bounds__(512, 4) void mlp_fused(
    const float* __restrict__ seq, const float* __restrict__ b1,
    const float* __restrict__ b2, const unsigned short* __restrict__ ws,
    float* __restrict__ out) {
  __shared__ __align__(16) unsigned short lds_h[8192];        // 16 KB, single
  __shared__ __align__(16) unsigned short lds_w2[2][16384];   // 2 x 32 KB

  const int tid  = threadIdx.x;
  const int lane = tid & 63;
  const int wave = tid >> 6;          // 0..7
  const int q    = lane >> 4;         // quad 0..3
  const int l15  = lane & 15;
  const int m0   = blockIdx.x * 128;
  const unsigned short* pW1 = ws;
  const unsigned short* pW2 = ws + 65536;

  // ---- prologue: DMA W2 chunk 0 -> lds_w2[0]; completes during the x phase.
  // Thread (wave,lane,it) covers bytes (it*512+tid)*16 = it*8192 + wave*1024 + lane*16:
  // wave-uniform base + lane*16 — exactly the DMA's fixed write pattern.
#pragma unroll
  for (int it = 0; it < 4; ++it)
    gload_lds16(&pW2[(size_t)(it * 512 + tid) * 8],
                &lds_w2[0][it * 4096 + wave * 512]);

  // ---- phase 0: x row-fragments into registers; first-neg scan; threefry dropout
  // Lane (l15, q) owns row (m0 + wave*16 + l15), k-octets [8q..8q+7] and [32+8q..39+8q].
  short8 xb[2];                        // GEMM1 B-frags: x[row][kb*32 + 8q + j]
  {
    const int row = m0 + wave * 16 + l15;
    const float* xrow = seq + (size_t)row * 50;
    float xv[2][8];
    unsigned long long nm = 0ull;
#pragma unroll
    for (int kb = 0; kb < 2; ++kb) {
#pragma unroll
      for (int jp = 0; jp < 4; ++jp) {
        const int k = kb * 32 + q * 8 + jp * 2;   // even, 8B-aligned
        float2 v;
        if (k < 50) v = *(const float2*)&xrow[k];
        else        v = make_float2(0.f, 0.f);    // K-pad with 0
        xv[kb][jp * 2]     = v.x;
        xv[kb][jp * 2 + 1] = v.y;
        if (v.x == -1.0f) nm |= 1ull << k;
        if (v.y == -1.0f) nm |= 1ull << (k + 1);
      }
    }
    // row's 4 owner lanes are {l15, l15+16, l15+32, l15+48}
    nm |= __shfl_xor(nm, 16);
    nm |= __shfl_xor(nm, 32);
    const int fn   = nm ? __builtin_ctzll(nm) : 64;   // first_neg (>=50 => all valid)
    const int kmax = fn < 50 ? fn : 50;
    const unsigned jbase = (unsigned)row * 50u;
#pragma unroll
    for (int kb = 0; kb < 2; ++kb) {
      short8 vv;
#pragma unroll
      for (int j = 0; j < 8; ++j) {
        const int k = kb * 32 + q * 8 + j;
        float v = xv[kb][j];
        if (k < kmax && drop_rand(jbase + (unsigned)k)) v = 0.0f;
        vv[j] = (short)f2bf(v);
      }
      xb[kb] = vv;
    }
  }

  f32x4 acc[4][4];
#pragma unroll
  for (int mt = 0; mt < 4; ++mt)
#pragma unroll
    for (int ni = 0; ni < 4; ++ni) acc[mt][ni] = f32x4{0.f, 0.f, 0.f, 0.f};

  const int rg  = wave >> 2;     // GEMM2 rows: rg*64 .. rg*64+63
  const int cgr = wave & 3;      // GEMM2 cols: cgr*64 .. cgr*64+63

  for (int c = 0; c < 16; ++c) {
    const int par = c & 1;

    // ---- GEMM1 (swapped): hacc[hi] = h[row = wave*16+l15][hcol = hi*16 + 4q + r]
    // wa loaded per-kb (16-reg transient) to cap register pressure.
    f32x4 hacc[4];
#pragma unroll
    for (int hi = 0; hi < 4; ++hi) hacc[hi] = f32x4{0.f, 0.f, 0.f, 0.f};
#pragma unroll
    for (int kb = 0; kb < 2; ++kb) {
      short8 wa[4];
#pragma unroll
      for (int hi = 0; hi < 4; ++hi)
        wa[hi] = *(const short8*)&pW1[(size_t)(((c * 4 + hi) * 2 + kb) * 64 + lane) * 8];
#pragma unroll
      for (int hi = 0; hi < 4; ++hi)
        hacc[hi] = __builtin_amdgcn_mfma_f32_16x16x32_bf16(wa[hi], xb[kb], hacc[hi], 0, 0, 0);
    }

    // ---- bias + relu + bf16 pack -> A-frag layout, 4 x ds_write_b64
    // hcol64 = hi*16 + 4q + r  ->  kb = hi>>1, q' = ((hi&1)<<1)|(q>>1), j0 = 4*(q&1)
#pragma unroll
    for (int hi = 0; hi < 4; ++hi) {
      const f32x4 bv = *(const f32x4*)&b1[c * 64 + hi * 16 + q * 4];
      const float v0 = fmaxf(hacc[hi][0] + bv[0], 0.f);
      const float v1 = fmaxf(hacc[hi][1] + bv[1], 0.f);
      const float v2 = fmaxf(hacc[hi][2] + bv[2], 0.f);
      const float v3 = fmaxf(hacc[hi][3] + bv[3], 0.f);
      const unsigned w0 = (unsigned)f2bf(v0) | ((unsigned)f2bf(v1) << 16);
      const unsigned w1 = (unsigned)f2bf(v2) | ((unsigned)f2bf(v3) << 16);
      const int kbx  = hi >> 1;
      const int qp   = ((hi & 1) << 1) | (q >> 1);
      const int elem = (wave * 2 + kbx) * 64 + qp * 16 + l15;
      uint2 val; val.x = w0; val.y = w1;
      *(uint2*)&lds_h[elem * 8 + (q & 1) * 4] = val;   // 8B-aligned ds_write_b64
    }

    __syncthreads();   // barrier A: h(c) visible; W2(c) DMA drained (vmcnt(0))

    // ---- issue DMA for W2(c+1) into the other buffer.
    // WAR safe: lds_w2[par^1] was last read by GEMM2(c-1), which finished at
    // barrier B(c-1) < A(c). Drained at B(c) (~GEMM2-length later) and at A(c+1).
    if (c < 15) {
#pragma unroll
      for (int it = 0; it < 4; ++it)
        gload_lds16(&pW2[(size_t)(c + 1) * 16384 + (size_t)(it * 512 + tid) * 8],
                    &lds_w2[par ^ 1][it * 4096 + wave * 512]);
    }

    // ---- GEMM2: acc += h_chunk @ W2[64c..64c+64, :) entirely from LDS
#pragma unroll
    for (int kb = 0; kb < 2; ++kb) {
      short8 ha[4], wb[4];
#pragma unroll
      for (int mt = 0; mt < 4; ++mt)
        ha[mt] = *(const short8*)&lds_h[(size_t)(((rg * 4 + mt) * 2 + kb) * 64 + lane) * 8];
#pragma unroll
      for (int ni = 0; ni < 4; ++ni)
        wb[ni] = *(const short8*)&lds_w2[par][(size_t)((kb * 16 + cgr * 4 + ni) * 64 + lane) * 8];
#pragma unroll
      for (int mt = 0; mt < 4; ++mt)
#pragma unroll
        for (int ni = 0; ni < 4; ++ni)
          acc[mt][ni] = __builtin_amdgcn_mfma_f32_16x16x32_bf16(ha[mt], wb[ni],
                                                                acc[mt][ni], 0, 0, 0);
    }

    if (c < 15) __syncthreads();   // barrier B: done reading lds_h & lds_w2[par]
  }

  // ---- epilogue: + b2, fp32 store (C-layout: 4-row x 16-col segments)
#pragma unroll
  for (int ni = 0; ni < 4; ++ni) {
    const int e = cgr * 64 + ni * 16 + l15;
    const float b2v = b2[e];
#pragma unroll
    for (int mt = 0; mt < 4; ++mt) {
      const int rbase = m0 + rg * 64 + mt * 16 + q * 4;
#pragma unroll
      for (int r = 0; r < 4; ++r)
        out[(size_t)(rbase + r) * 256 + e] = acc[mt][ni][r] + b2v;
    }
  }
}

extern "C" void kernel_launch(void* const* d_in, const int* in_sizes, int n_in,
                              void* d_out, int out_size, void* d_ws, size_t ws_size,
                              hipStream_t stream) {
  const float* seq = (const float*)d_in[0];
  const float* W1  = (const float*)d_in[1];
  const float* b1  = (const float*)d_in[2];
  const float* W2  = (const float*)d_in[3];
  const float* b2  = (const float*)d_in[4];
  unsigned short* ws = (unsigned short*)d_ws;   // 655360 bytes used
  float* out = (float*)d_out;

  hipLaunchKernelGGL(pack_weights, dim3(160), dim3(256), 0, stream, W1, W2, ws);
  hipLaunchKernelGGL(mlp_fused, dim3(2048), dim3(512), 0, stream, seq, b1, b2, ws, out);
}

// Round 5
// 494.078 us; speedup vs baseline: 1.6046x; 1.0648x over previous
//
#include <hip/hip_runtime.h>

// SeqFCEncoder: out = relu(drop(x) @ W1 + b1) @ W2 + b2
// B=262144 rows, L=50 (K-padded to 64), H=1024 (16 chunks of 64), E=256.
// bf16 MFMA 16x16x32 fused pipeline; weights pre-packed into fragment order in ws.
//
// v5 = v4 + decoupled DMA drain (T4 counted-wait discipline via vmcnt FIFO):
//  - Barrier A: s_waitcnt lgkmcnt(0) + raw s_barrier (NO vmcnt drain).
//  - Barrier B: raw s_barrier only.
//  - DMA W2(c+1) issued between GEMM1(c) and pack(c), sched_barrier-fenced so it
//    stays AFTER the wa(c) loads. vmcnt FIFO: GEMM1(c)'s auto-wait for wa(c) is
//    vmcnt(4), which retires DMA W2(c) (issued one full chunk earlier, ~1.5k cy
//    of cover) while leaving DMA W2(c+1) in flight. No barrier drains a fresh DMA.
//  - pack uses v_cvt_pk_bf16_f32 (1 op per 2 values) instead of 3-op f2bf.
//  - Everything else identical to v4: 80 KB LDS (2 blocks/CU), x in regs,
//    swapped GEMM1, 4x ds_write_b64 h transpose, GEMM2 64x64 wave tiles.

typedef __attribute__((ext_vector_type(8))) short short8;   // 8 bf16 = one MFMA operand frag
typedef __attribute__((ext_vector_type(4))) float f32x4;    // MFMA accumulator frag

__device__ __forceinline__ unsigned short f2bf(float f) {
  unsigned u = __float_as_uint(f);
  u += 0x7fffu + ((u >> 16) & 1u);           // round-to-nearest-even
  return (unsigned short)(u >> 16);
}

__device__ __forceinline__ unsigned rotl_(unsigned x, int d) {
  return (x << d) | (x >> (32 - d));
}

// Partitionable threefry2x32: key=(0,42), counter=(0, j); 20 rounds; bits=v0^v1.
// uniform: bitcast((bits>>9)|0x3f800000) - 1.0f;  drop iff u < 0.2f
__device__ __forceinline__ bool drop_rand(unsigned j) {
  const unsigned k0 = 0u, k1 = 42u, k2 = 0x1BD11BDAu ^ 42u;
  unsigned v0 = 0u + k0;          // counter hi word = 0
  unsigned v1 = j + k1;           // counter lo word = flat index
#define MIX(rot) { v0 += v1; v1 = rotl_(v1, rot); v1 ^= v0; }
  MIX(13) MIX(15) MIX(26) MIX(6)   v0 += k1; v1 += k2 + 1u;
  MIX(17) MIX(29) MIX(16) MIX(24)  v0 += k2; v1 += k0 + 2u;
  MIX(13) MIX(15) MIX(26) MIX(6)   v0 += k0; v1 += k1 + 3u;
  MIX(17) MIX(29) MIX(16) MIX(24)  v0 += k1; v1 += k2 + 4u;
  MIX(13) MIX(15) MIX(26) MIX(6)   v0 += k2; v1 += k0 + 5u;
#undef MIX
  unsigned bits = v0 ^ v1;
  float u = __uint_as_float((bits >> 9) | 0x3f800000u) - 1.0f;
  return u < 0.2f;
}

// Async 16B global -> LDS (DMA): per-lane global src, wave-uniform LDS base;
// HW writes lds_base + lane*16. Counts toward vmcnt.
__device__ __forceinline__ void gload_lds16(const unsigned short* g, unsigned short* l) {
  __builtin_amdgcn_global_load_lds(
      (const __attribute__((address_space(1))) unsigned int*)g,
      (__attribute__((address_space(3))) unsigned int*)l, 16, 0, 0);
}

// pack 2 f32 -> 1 dword of 2 bf16 (RNE), low=a, high=b
__device__ __forceinline__ unsigned cvt_pk_bf16(float a, float b) {
  unsigned r;
  asm("v_cvt_pk_bf16_f32 %0, %1, %2" : "=v"(r) : "v"(a), "v"(b));
  return r;
}

// ---------------------------------------------------------------------------
// Prep: pack W1 (50x1024, K-padded to 64) and W2 (1024x256) as bf16 in MFMA
// fragment order. Fragment (lane, j) holds W[kblk*32 + (lane>>4)*8 + j][nt*16 + (lane&15)].
//   pW1 @ ws[0]:      [nblk 0..63][kb 0..1][lane][j]          = 65536 elems (128 KB)
//   pW2 @ ws[65536]:  [c 0..15][kb 0..1][nt 0..15][lane][j]   = 262144 elems (512 KB)
// A-frag and B-frag lane layouts are identical, so pW1 serves as the A operand
// of the swapped GEMM1 and pW2 as the B operand of GEMM2.
// ---------------------------------------------------------------------------
__global__ void pack_weights(const float* __restrict__ W1, const float* __restrict__ W2,
                             unsigned short* __restrict__ ws) {
  int t = blockIdx.x * 256 + threadIdx.x;   // 0..40959
  if (t < 8192) {
    int nblk = t >> 7, kb = (t >> 6) & 1, lane = t & 63;
    int kbase = kb * 32 + ((lane >> 4) * 8);
    int col = nblk * 16 + (lane & 15);
    short8 vv;
#pragma unroll
    for (int j = 0; j < 8; ++j) {
      int k = kbase + j;
      vv[j] = (short)((k < 50) ? f2bf(W1[k * 1024 + col]) : (unsigned short)0);
    }
    *(short8*)&ws[t * 8] = vv;
  } else {
    int t2 = t - 8192;                       // 0..32767
    int c = t2 >> 11, kb = (t2 >> 10) & 1, nt = (t2 >> 6) & 15, lane = t2 & 63;
    int kbase = c * 64 + kb * 32 + ((lane >> 4) * 8);
    int e = nt * 16 + (lane & 15);
    short8 vv;
#pragma unroll
    for (int j = 0; j < 8; ++j) vv[j] = (short)f2bf(W2[(size_t)(kbase + j) * 256 + e]);
    *(short8*)&ws[65536 + t2 * 8] = vv;
  }
}

// ---------------------------------------------------------------------------
// Fused MLP. 512 threads (8 waves), 128 rows/block, grid 2048, 2 blocks/CU.
//   GEMM1: wave w owns rows w*16..w*16+15 (swapped MFMA, 8 MFMA/chunk).
//   GEMM2: wave = (rg = wave>>2: 64 rows) x (cgr = wave&3: 64 E-cols), acc[4][4].
// LDS: lds_h[16KB] + lds_w2[2][32KB] = 80 KB exactly.
// ---------------------------------------------------------------------------
__global__ __launch_bounds__(512, 4) void mlp_fused(
    const float* __restrict__ seq, const float* __restrict__ b1,
    const float* __restrict__ b2, const unsigned short* __restrict__ ws,
    float* __restrict__ out) {
  __shared__ __align__(16) unsigned short lds_h[8192];        // 16 KB, single
  __shared__ __align__(16) unsigned short lds_w2[2][16384];   // 2 x 32 KB

  const int tid  = threadIdx.x;
  const int lane = tid & 63;
  const int wave = tid >> 6;          // 0..7
  const int q    = lane >> 4;         // quad 0..3
  const int l15  = lane & 15;
  const int m0   = blockIdx.x * 128;
  const unsigned short* pW1 = ws;
  const unsigned short* pW2 = ws + 65536;

  // ---- prologue: DMA W2 chunk 0 -> lds_w2[0]; completes during the x phase.
  // Thread (wave,lane,it) covers bytes (it*512+tid)*16 = it*8192 + wave*1024 + lane*16:
  // wave-uniform base + lane*16 — exactly the DMA's fixed write pattern.
#pragma unroll
  for (int it = 0; it < 4; ++it)
    gload_lds16(&pW2[(size_t)(it * 512 + tid) * 8],
                &lds_w2[0][it * 4096 + wave * 512]);

  // ---- phase 0: x row-fragments into registers; first-neg scan; threefry dropout
  // Lane (l15, q) owns row (m0 + wave*16 + l15), k-octets [8q..8q+7] and [32+8q..39+8q].
  short8 xb[2];                        // GEMM1 B-frags: x[row][kb*32 + 8q + j]
  {
    const int row = m0 + wave * 16 + l15;
    const float* xrow = seq + (size_t)row * 50;
    float xv[2][8];
    unsigned long long nm = 0ull;
#pragma unroll
    for (int kb = 0; kb < 2; ++kb) {
#pragma unroll
      for (int jp = 0; jp < 4; ++jp) {
        const int k = kb * 32 + q * 8 + jp * 2;   // even, 8B-aligned
        float2 v;
        if (k < 50) v = *(const float2*)&xrow[k];
        else        v = make_float2(0.f, 0.f);    // K-pad with 0
        xv[kb][jp * 2]     = v.x;
        xv[kb][jp * 2 + 1] = v.y;
        if (v.x == -1.0f) nm |= 1ull << k;
        if (v.y == -1.0f) nm |= 1ull << (k + 1);
      }
    }
    // row's 4 owner lanes are {l15, l15+16, l15+32, l15+48}
    nm |= __shfl_xor(nm, 16);
    nm |= __shfl_xor(nm, 32);
    const int fn   = nm ? __builtin_ctzll(nm) : 64;   // first_neg (>=50 => all valid)
    const int kmax = fn < 50 ? fn : 50;
    const unsigned jbase = (unsigned)row * 50u;
#pragma unroll
    for (int kb = 0; kb < 2; ++kb) {
      short8 vv;
#pragma unroll
      for (int j = 0; j < 8; ++j) {
        const int k = kb * 32 + q * 8 + j;
        float v = xv[kb][j];
        if (k < kmax && drop_rand(jbase + (unsigned)k)) v = 0.0f;
        vv[j] = (short)f2bf(v);
      }
      xb[kb] = vv;
    }
  }

  f32x4 acc[4][4];
#pragma unroll
  for (int mt = 0; mt < 4; ++mt)
#pragma unroll
    for (int ni = 0; ni < 4; ++ni) acc[mt][ni] = f32x4{0.f, 0.f, 0.f, 0.f};

  const int rg  = wave >> 2;     // GEMM2 rows: rg*64 .. rg*64+63
  const int cgr = wave & 3;      // GEMM2 cols: cgr*64 .. cgr*64+63

  for (int c = 0; c < 16; ++c) {
    const int par = c & 1;

    // ---- GEMM1 (swapped): hacc[hi] = h[row = wave*16+l15][hcol = hi*16 + 4q + r]
    // wa loaded per-kb (16-reg transient). The auto-inserted vmcnt wait for wa
    // retires DMA W2(c) (older in the vmem FIFO, issued a full chunk ago) while
    // DMA W2(c+1) has not been issued yet.
    f32x4 hacc[4];
#pragma unroll
    for (int hi = 0; hi < 4; ++hi) hacc[hi] = f32x4{0.f, 0.f, 0.f, 0.f};
#pragma unroll
    for (int kb = 0; kb < 2; ++kb) {
      short8 wa[4];
#pragma unroll
      for (int hi = 0; hi < 4; ++hi)
        wa[hi] = *(const short8*)&pW1[(size_t)(((c * 4 + hi) * 2 + kb) * 64 + lane) * 8];
#pragma unroll
      for (int hi = 0; hi < 4; ++hi)
        hacc[hi] = __builtin_amdgcn_mfma_f32_16x16x32_bf16(wa[hi], xb[kb], hacc[hi], 0, 0, 0);
    }

    // ---- issue DMA for W2(c+1) into the other buffer, fenced so it stays AFTER
    // the wa loads (vmem FIFO order!) and is not sunk past the pack/barrier.
    // WAR safe: lds_w2[par^1] was last read by GEMM2(c-1), before barrier B(c-1).
    // Drain point: GEMM1(c+1)'s wa wait (vmcnt(4)) — one full chunk of cover.
    if (c < 15) {
      __builtin_amdgcn_sched_barrier(0);
#pragma unroll
      for (int it = 0; it < 4; ++it)
        gload_lds16(&pW2[(size_t)(c + 1) * 16384 + (size_t)(it * 512 + tid) * 8],
                    &lds_w2[par ^ 1][it * 4096 + wave * 512]);
      __builtin_amdgcn_sched_barrier(0);
    }

    // ---- bias + relu + cvt_pk bf16 -> A-frag layout, 4 x ds_write_b64
    // hcol64 = hi*16 + 4q + r  ->  kb = hi>>1, q' = ((hi&1)<<1)|(q>>1), j0 = 4*(q&1)
#pragma unroll
    for (int hi = 0; hi < 4; ++hi) {
      const f32x4 bv = *(const f32x4*)&b1[c * 64 + hi * 16 + q * 4];
      const float v0 = fmaxf(hacc[hi][0] + bv[0], 0.f);
      const float v1 = fmaxf(hacc[hi][1] + bv[1], 0.f);
      const float v2 = fmaxf(hacc[hi][2] + bv[2], 0.f);
      const float v3 = fmaxf(hacc[hi][3] + bv[3], 0.f);
      const unsigned w0 = cvt_pk_bf16(v0, v1);
      const unsigned w1 = cvt_pk_bf16(v2, v3);
      const int kbx  = hi >> 1;
      const int qp   = ((hi & 1) << 1) | (q >> 1);
      const int elem = (wave * 2 + kbx) * 64 + qp * 16 + l15;
      uint2 val; val.x = w0; val.y = w1;
      *(uint2*)&lds_h[elem * 8 + (q & 1) * 4] = val;   // 8B-aligned ds_write_b64
    }

    // ---- barrier A: pack(c) visible, lds_w2[par] (DMA'd chunk c) readable.
    // NO vmcnt drain here — DMA W2(c) was already retired by GEMM1(c)'s wa wait;
    // DMA W2(c+1) stays in flight across this barrier.
    __builtin_amdgcn_sched_barrier(0);
    asm volatile("s_waitcnt lgkmcnt(0)" ::: "memory");
    __builtin_amdgcn_sched_barrier(0);
    __builtin_amdgcn_s_barrier();
    __builtin_amdgcn_sched_barrier(0);

    // ---- GEMM2: acc += h_chunk @ W2[64c..64c+64, :) entirely from LDS
#pragma unroll
    for (int kb = 0; kb < 2; ++kb) {
      short8 ha[4], wb[4];
#pragma unroll
      for (int mt = 0; mt < 4; ++mt)
        ha[mt] = *(const short8*)&lds_h[(size_t)(((rg * 4 + mt) * 2 + kb) * 64 + lane) * 8];
#pragma unroll
      for (int ni = 0; ni < 4; ++ni)
        wb[ni] = *(const short8*)&lds_w2[par][(size_t)((kb * 16 + cgr * 4 + ni) * 64 + lane) * 8];
#pragma unroll
      for (int mt = 0; mt < 4; ++mt)
#pragma unroll
        for (int ni = 0; ni < 4; ++ni)
          acc[mt][ni] = __builtin_amdgcn_mfma_f32_16x16x32_bf16(ha[mt], wb[ni],
                                                                acc[mt][ni], 0, 0, 0);
    }

    // ---- barrier B: all GEMM2 reads of lds_h / lds_w2[par] are consumed by the
    // MFMAs above (data-dependence lgkm waits), so a bare barrier suffices.
    // Crucially: no vmcnt drain — DMA W2(c+1) keeps flying.
    if (c < 15) {
      __builtin_amdgcn_sched_barrier(0);
      __builtin_amdgcn_s_barrier();
      __builtin_amdgcn_sched_barrier(0);
    }
  }

  // ---- epilogue: + b2, fp32 store (C-layout: 4-row x 16-col segments)
#pragma unroll
  for (int ni = 0; ni < 4; ++ni) {
    const int e = cgr * 64 + ni * 16 + l15;
    const float b2v = b2[e];
#pragma unroll
    for (int mt = 0; mt < 4; ++mt) {
      const int rbase = m0 + rg * 64 + mt * 16 + q * 4;
#pragma unroll
      for (int r = 0; r < 4; ++r)
        out[(size_t)(rbase + r) * 256 + e] = acc[mt][ni][r] + b2v;
    }
  }
}

extern "C" void kernel_launch(void* const* d_in, const int* in_sizes, int n_in,
                              void* d_out, int out_size, void* d_ws, size_t ws_size,
                              hipStream_t stream) {
  const float* seq = (const float*)d_in[0];
  const float* W1  = (const float*)d_in[1];
  const float* b1  = (const float*)d_in[2];
  const float* W2  = (const float*)d_in[3];
  const float* b2  = (const float*)d_in[4];
  unsigned short* ws = (unsigned short*)d_ws;   // 655360 bytes used
  float* out = (float*)d_out;

  hipLaunchKernelGGL(pack_weights, dim3(160), dim3(256), 0, stream, W1, W2, ws);
  hipLaunchKernelGGL(mlp_fused, dim3(2048), dim3(512), 0, stream, seq, b1, b2, ws, out);
}

// Round 6
// 491.542 us; speedup vs baseline: 1.6129x; 1.0052x over previous
//
#include <hip/hip_runtime.h>

// SeqFCEncoder: out = relu(drop(x) @ W1 + b1) @ W2 + b2
// B=262144 rows, L=50 (K-padded to 64), H=1024 (16 chunks of 64), E=256.
// bf16 MFMA 16x16x32 fused pipeline; weights pre-packed into fragment order in ws.
//
// v6 = v5 with the chunk pipeline re-cut so the serial B->A segment is minimal:
//   iteration i:  A -> [GEMM2(i)  ||  GEMM1(i+1) (no LDS)] -> B -> [DMA W2(i+2), pack(i+1)] -> A
//  - GEMM1(i+1) sits in the barrier-free region: its wa-load latency and MFMAs
//    overlap GEMM2(i)'s ds_reads/MFMAs instead of being exposed after B.
//  - DMA W2 is issued a FULL iteration ahead (tail of i stages chunk i+2).
//    vmem FIFO discipline: GEMM1(i+1)'s auto-wait for wa retires the older
//    DMA(i+1) before A(i+1) consumes it, while DMA(i+2) (younger) stays in
//    flight across A. No hand-written vmcnt required.
//  - b1 folded into GEMM1's accumulator init (C row = hcol) -> pack is just
//    relu+cvt_pk+4 ds_write_b64.
//  - LDS 80 KB (h 16K + w2 2x32K), regs <=128 -> 2 blocks/CU (16 waves).

typedef __attribute__((ext_vector_type(8))) short short8;   // 8 bf16 = one MFMA operand frag
typedef __attribute__((ext_vector_type(4))) float f32x4;    // MFMA accumulator frag

__device__ __forceinline__ unsigned short f2bf(float f) {
  unsigned u = __float_as_uint(f);
  u += 0x7fffu + ((u >> 16) & 1u);           // round-to-nearest-even
  return (unsigned short)(u >> 16);
}

__device__ __forceinline__ unsigned rotl_(unsigned x, int d) {
  return (x << d) | (x >> (32 - d));
}

// Partitionable threefry2x32: key=(0,42), counter=(0, j); 20 rounds; bits=v0^v1.
// uniform: bitcast((bits>>9)|0x3f800000) - 1.0f;  drop iff u < 0.2f
__device__ __forceinline__ bool drop_rand(unsigned j) {
  const unsigned k0 = 0u, k1 = 42u, k2 = 0x1BD11BDAu ^ 42u;
  unsigned v0 = 0u + k0;          // counter hi word = 0
  unsigned v1 = j + k1;           // counter lo word = flat index
#define MIX(rot) { v0 += v1; v1 = rotl_(v1, rot); v1 ^= v0; }
  MIX(13) MIX(15) MIX(26) MIX(6)   v0 += k1; v1 += k2 + 1u;
  MIX(17) MIX(29) MIX(16) MIX(24)  v0 += k2; v1 += k0 + 2u;
  MIX(13) MIX(15) MIX(26) MIX(6)   v0 += k0; v1 += k1 + 3u;
  MIX(17) MIX(29) MIX(16) MIX(24)  v0 += k1; v1 += k2 + 4u;
  MIX(13) MIX(15) MIX(26) MIX(6)   v0 += k2; v1 += k0 + 5u;
#undef MIX
  unsigned bits = v0 ^ v1;
  float u = __uint_as_float((bits >> 9) | 0x3f800000u) - 1.0f;
  return u < 0.2f;
}

// Async 16B global -> LDS (DMA): per-lane global src, wave-uniform LDS base;
// HW writes lds_base + lane*16. Counts toward vmcnt.
__device__ __forceinline__ void gload_lds16(const unsigned short* g, unsigned short* l) {
  __builtin_amdgcn_global_load_lds(
      (const __attribute__((address_space(1))) unsigned int*)g,
      (__attribute__((address_space(3))) unsigned int*)l, 16, 0, 0);
}

// pack 2 f32 -> 1 dword of 2 bf16 (RNE), low=a, high=b
__device__ __forceinline__ unsigned cvt_pk_bf16(float a, float b) {
  unsigned r;
  asm("v_cvt_pk_bf16_f32 %0, %1, %2" : "=v"(r) : "v"(a), "v"(b));
  return r;
}

// ---------------------------------------------------------------------------
// Prep: pack W1 (50x1024, K-padded to 64) and W2 (1024x256) as bf16 in MFMA
// fragment order. Fragment (lane, j) holds W[kblk*32 + (lane>>4)*8 + j][nt*16 + (lane&15)].
//   pW1 @ ws[0]:      [nblk 0..63][kb 0..1][lane][j]          = 65536 elems (128 KB)
//   pW2 @ ws[65536]:  [c 0..15][kb 0..1][nt 0..15][lane][j]   = 262144 elems (512 KB)
// A-frag and B-frag lane layouts are identical, so pW1 serves as the A operand
// of the swapped GEMM1 and pW2 as the B operand of GEMM2.
// ---------------------------------------------------------------------------
__global__ void pack_weights(const float* __restrict__ W1, const float* __restrict__ W2,
                             unsigned short* __restrict__ ws) {
  int t = blockIdx.x * 256 + threadIdx.x;   // 0..40959
  if (t < 8192) {
    int nblk = t >> 7, kb = (t >> 6) & 1, lane = t & 63;
    int kbase = kb * 32 + ((lane >> 4) * 8);
    int col = nblk * 16 + (lane & 15);
    short8 vv;
#pragma unroll
    for (int j = 0; j < 8; ++j) {
      int k = kbase + j;
      vv[j] = (short)((k < 50) ? f2bf(W1[k * 1024 + col]) : (unsigned short)0);
    }
    *(short8*)&ws[t * 8] = vv;
  } else {
    int t2 = t - 8192;                       // 0..32767
    int c = t2 >> 11, kb = (t2 >> 10) & 1, nt = (t2 >> 6) & 15, lane = t2 & 63;
    int kbase = c * 64 + kb * 32 + ((lane >> 4) * 8);
    int e = nt * 16 + (lane & 15);
    short8 vv;
#pragma unroll
    for (int j = 0; j < 8; ++j) vv[j] = (short)f2bf(W2[(size_t)(kbase + j) * 256 + e]);
    *(short8*)&ws[65536 + t2 * 8] = vv;
  }
}

// ---------------------------------------------------------------------------
// Fused MLP. 512 threads (8 waves), 128 rows/block, grid 2048, 2 blocks/CU.
//   GEMM1: wave w owns rows w*16..w*16+15 (swapped MFMA, 8 MFMA/chunk).
//   GEMM2: wave = (rg = wave>>2: 64 rows) x (cgr = wave&3: 64 E-cols), acc[4][4].
// LDS: lds_h[16KB] + lds_w2[2][32KB] = 80 KB exactly.
// ---------------------------------------------------------------------------
__global__ __launch_bounds__(512, 4) void mlp_fused(
    const float* __restrict__ seq, const float* __restrict__ b1,
    const float* __restrict__ b2, const unsigned short* __restrict__ ws,
    float* __restrict__ out) {
  __shared__ __align__(16) unsigned short lds_h[8192];        // 16 KB, single
  __shared__ __align__(16) unsigned short lds_w2[2][16384];   // 2 x 32 KB

  const int tid  = threadIdx.x;
  const int lane = tid & 63;
  const int wave = tid >> 6;          // 0..7
  const int q    = lane >> 4;         // quad 0..3
  const int l15  = lane & 15;
  const int m0   = blockIdx.x * 128;
  const unsigned short* pW1 = ws;
  const unsigned short* pW2 = ws + 65536;

  // ---- prologue: DMA W2 chunks 0 AND 1 (both buffers); x phase gives cover.
  // Thread (wave,lane,it) covers bytes it*8192 + wave*1024 + lane*16:
  // wave-uniform base + lane*16 — exactly the DMA's fixed write pattern.
#pragma unroll
  for (int it = 0; it < 4; ++it)
    gload_lds16(&pW2[(size_t)(it * 512 + tid) * 8],
                &lds_w2[0][it * 4096 + wave * 512]);
#pragma unroll
  for (int it = 0; it < 4; ++it)
    gload_lds16(&pW2[16384 + (size_t)(it * 512 + tid) * 8],
                &lds_w2[1][it * 4096 + wave * 512]);

  // ---- phase 0: x row-fragments into registers; first-neg scan; threefry dropout
  // Lane (l15, q) owns row (m0 + wave*16 + l15), k-octets [8q..8q+7] and [32+8q..39+8q].
  short8 xb[2];                        // GEMM1 B-frags: x[row][kb*32 + 8q + j]
  {
    const int row = m0 + wave * 16 + l15;
    const float* xrow = seq + (size_t)row * 50;
    float xv[2][8];
    unsigned long long nm = 0ull;
#pragma unroll
    for (int kb = 0; kb < 2; ++kb) {
#pragma unroll
      for (int jp = 0; jp < 4; ++jp) {
        const int k = kb * 32 + q * 8 + jp * 2;   // even, 8B-aligned
        float2 v;
        if (k < 50) v = *(const float2*)&xrow[k];
        else        v = make_float2(0.f, 0.f);    // K-pad with 0
        xv[kb][jp * 2]     = v.x;
        xv[kb][jp * 2 + 1] = v.y;
        if (v.x == -1.0f) nm |= 1ull << k;
        if (v.y == -1.0f) nm |= 1ull << (k + 1);
      }
    }
    // row's 4 owner lanes are {l15, l15+16, l15+32, l15+48}
    nm |= __shfl_xor(nm, 16);
    nm |= __shfl_xor(nm, 32);
    const int fn   = nm ? __builtin_ctzll(nm) : 64;   // first_neg (>=50 => all valid)
    const int kmax = fn < 50 ? fn : 50;
    const unsigned jbase = (unsigned)row * 50u;
#pragma unroll
    for (int kb = 0; kb < 2; ++kb) {
      short8 vv;
#pragma unroll
      for (int j = 0; j < 8; ++j) {
        const int k = kb * 32 + q * 8 + j;
        float v = xv[kb][j];
        if (k < kmax && drop_rand(jbase + (unsigned)k)) v = 0.0f;
        vv[j] = (short)f2bf(v);
      }
      xb[kb] = vv;
    }
  }

  // GEMM1 for chunk c -> hnext. hacc C-layout: row = hcol (within chunk),
  // col = l15 = batch row, so init C = b1 broadcast gives bias for free.
  f32x4 hnext[4];
#define GEMM1_STEP(C)                                                                \
  {                                                                                  \
    const int c_ = (C);                                                              \
    _Pragma("unroll")                                                                \
    for (int hi = 0; hi < 4; ++hi)                                                   \
      hnext[hi] = *(const f32x4*)&b1[c_ * 64 + hi * 16 + q * 4];                     \
    _Pragma("unroll")                                                                \
    for (int kb = 0; kb < 2; ++kb) {                                                 \
      short8 wa[4];                                                                  \
      _Pragma("unroll")                                                              \
      for (int hi = 0; hi < 4; ++hi)                                                 \
        wa[hi] = *(const short8*)&pW1[(size_t)(((c_ * 4 + hi) * 2 + kb) * 64 + lane) * 8]; \
      _Pragma("unroll")                                                              \
      for (int hi = 0; hi < 4; ++hi)                                                 \
        hnext[hi] = __builtin_amdgcn_mfma_f32_16x16x32_bf16(wa[hi], xb[kb],          \
                                                            hnext[hi], 0, 0, 0);     \
    }                                                                                \
  }

  // pack hnext -> lds_h (A-frag layout): relu + cvt_pk + 4 x ds_write_b64.
  // hcol64 = hi*16 + 4q + r -> kb = hi>>1, q' = ((hi&1)<<1)|(q>>1), j0 = 4*(q&1)
#define PACK_STEP()                                                                  \
  {                                                                                  \
    _Pragma("unroll")                                                                \
    for (int hi = 0; hi < 4; ++hi) {                                                 \
      const float v0 = fmaxf(hnext[hi][0], 0.f);                                     \
      const float v1 = fmaxf(hnext[hi][1], 0.f);                                     \
      const float v2 = fmaxf(hnext[hi][2], 0.f);                                     \
      const float v3 = fmaxf(hnext[hi][3], 0.f);                                     \
      const unsigned w0 = cvt_pk_bf16(v0, v1);                                       \
      const unsigned w1 = cvt_pk_bf16(v2, v3);                                       \
      const int kbx  = hi >> 1;                                                      \
      const int qp   = ((hi & 1) << 1) | (q >> 1);                                   \
      const int elem = (wave * 2 + kbx) * 64 + qp * 16 + l15;                        \
      uint2 val; val.x = w0; val.y = w1;                                             \
      *(uint2*)&lds_h[elem * 8 + (q & 1) * 4] = val;                                 \
    }                                                                                \
  }

  // ---- prologue GEMM1(0) + pack(0). Its wa-wait (vmcnt) drains both prologue
  // DMAs (older in FIFO) — they had the whole x phase in flight.
  GEMM1_STEP(0)
  PACK_STEP()

  f32x4 acc[4][4];
#pragma unroll
  for (int mt = 0; mt < 4; ++mt)
#pragma unroll
    for (int ni = 0; ni < 4; ++ni) acc[mt][ni] = f32x4{0.f, 0.f, 0.f, 0.f};

  const int rg  = wave >> 2;     // GEMM2 rows: rg*64 .. rg*64+63
  const int cgr = wave & 3;      // GEMM2 cols: cgr*64 .. cgr*64+63

  // ---- barrier A(0): pack(0) visible, lds_w2[0] ready (DMA drained above).
  asm volatile("s_waitcnt lgkmcnt(0)" ::: "memory");
  __builtin_amdgcn_s_barrier();
  __builtin_amdgcn_sched_barrier(0);

  for (int i = 0; i < 16; ++i) {
    const int par = i & 1;
    const unsigned short* w2cur = &lds_w2[par][0];

    // ---- GEMM2(i): acc += h(i) @ W2(i); 16 ds_read_b128 + 32 MFMA.
#pragma unroll
    for (int kb = 0; kb < 2; ++kb) {
      short8 ha[4], wb[4];
#pragma unroll
      for (int mt = 0; mt < 4; ++mt)
        ha[mt] = *(const short8*)&lds_h[(size_t)(((rg * 4 + mt) * 2 + kb) * 64 + lane) * 8];
#pragma unroll
      for (int ni = 0; ni < 4; ++ni)
        wb[ni] = *(const short8*)&w2cur[(size_t)((kb * 16 + cgr * 4 + ni) * 64 + lane) * 8];
#pragma unroll
      for (int mt = 0; mt < 4; ++mt)
#pragma unroll
        for (int ni = 0; ni < 4; ++ni)
          acc[mt][ni] = __builtin_amdgcn_mfma_f32_16x16x32_bf16(ha[mt], wb[ni],
                                                                acc[mt][ni], 0, 0, 0);
    }

    if (i < 15) {
      // ---- GEMM1(i+1): no LDS — overlaps GEMM2 above in the same region.
      // Its wa-load wait retires DMA(i+1) (older, issued last tail / prologue)
      // BEFORE barrier A(i+1) publishes lds_w2[par^1]. DMA(i+2) is younger and
      // stays in flight.
      GEMM1_STEP(i + 1)

      __builtin_amdgcn_sched_barrier(0);
      __builtin_amdgcn_s_barrier();          // B(i): lds_h / lds_w2[par] reads done
      __builtin_amdgcn_sched_barrier(0);

      // ---- DMA W2(i+2) into lds_w2[par] (just freed by GEMM2(i); WAR safe).
      // In flight across A(i+1) and the whole next iteration.
      if (i < 14) {
#pragma unroll
        for (int it = 0; it < 4; ++it)
          gload_lds16(&pW2[(size_t)(i + 2) * 16384 + (size_t)(it * 512 + tid) * 8],
                      &lds_w2[par][it * 4096 + wave * 512]);
      }

      // ---- pack(i+1) -> lds_h (the only work on the B->A critical path)
      PACK_STEP()

      asm volatile("s_waitcnt lgkmcnt(0)" ::: "memory");
      __builtin_amdgcn_s_barrier();          // A(i+1): h(i+1) + W2(i+1) ready
      __builtin_amdgcn_sched_barrier(0);
    }
  }
#undef GEMM1_STEP
#undef PACK_STEP

  // ---- epilogue: + b2, fp32 store (C-layout: 4-row x 16-col segments)
#pragma unroll
  for (int ni = 0; ni < 4; ++ni) {
    const int e = cgr * 64 + ni * 16 + l15;
    const float b2v = b2[e];
#pragma unroll
    for (int mt = 0; mt < 4; ++mt) {
      const int rbase = m0 + rg * 64 + mt * 16 + q * 4;
#pragma unroll
      for (int r = 0; r < 4; ++r)
        out[(size_t)(rbase + r) * 256 + e] = acc[mt][ni][r] + b2v;
    }
  }
}

extern "C" void kernel_launch(void* const* d_in, const int* in_sizes, int n_in,
                              void* d_out, int out_size, void* d_ws, size_t ws_size,
                              hipStream_t stream) {
  const float* seq = (const float*)d_in[0];
  const float* W1  = (const float*)d_in[1];
  const float* b1  = (const float*)d_in[2];
  const float* W2  = (const float*)d_in[3];
  const float* b2  = (const float*)d_in[4];
  unsigned short* ws = (unsigned short*)d_ws;   // 655360 bytes used
  float* out = (float*)d_out;

  hipLaunchKernelGGL(pack_weights, dim3(160), dim3(256), 0, stream, W1, W2, ws);
  hipLaunchKernelGGL(mlp_fused, dim3(2048), dim3(512), 0, stream, seq, b1, b2, ws, out);
}